// Round 1
// baseline (209.358 us; speedup 1.0000x reference)
//
#include <hip/hip_runtime.h>

// Problem constants (B,C,H,W) = (8,19,512,512), fp32 everywhere.
constexpr int B_ = 8, C_ = 19, H_ = 512, W_ = 512;
constexpr int HW_ = H_ * W_;

// ---------------- horizontal (along H) blur ----------------
// Block: 256 threads over w. Each thread produces TH consecutive h outputs
// via a register sliding window of TH+K-1 values. Reflect boundary (numpy
// 'reflect', edge excluded): i<0 -> -i ; i>=H -> 2H-2-i (pad < H so single
// reflection suffices).
template<int K, int TH>
__global__ void __launch_bounds__(256)
blur_h_kern(const float* __restrict__ src, long srcBatchStride,
            float* __restrict__ dst, float sigma)
{
    constexpr int PAD = K / 2;
    constexpr int NV = TH + K - 1;
    __shared__ float wk[K + 1];
    const int tid = threadIdx.x;
    if (tid < K) { float t = (tid - PAD) / sigma; wk[tid] = expf(-0.5f * t * t); }
    __syncthreads();
    if (tid == 0) { float s = 0.f; for (int k = 0; k < K; ++k) s += wk[k]; wk[K] = 1.f / s; }
    __syncthreads();
    if (tid < K) wk[tid] *= wk[K];
    __syncthreads();

    const int w  = blockIdx.x * 256 + tid;
    const int hb = blockIdx.y * TH;
    const int b  = blockIdx.z;
    const float* sb = src + (long)b * srcBatchStride;
    float* db = dst + (long)b * HW_;

    float vals[NV];
#pragma unroll
    for (int j = 0; j < NV; ++j) {
        int r = hb - PAD + j;
        r = (r < 0) ? -r : r;
        r = (r >= H_) ? (2 * H_ - 2 - r) : r;
        vals[j] = sb[(long)r * W_ + w];
    }
#pragma unroll
    for (int o = 0; o < TH; ++o) {
        float acc = 0.f;
#pragma unroll
        for (int k = 0; k < K; ++k) acc = fmaf(vals[o + k], wk[k], acc);
        db[(long)(hb + o) * W_ + w] = acc;
    }
}

// ---------------- vertical (along W) blur + eye-mask multiply + batch max ----
// One 512-thread block per (row, batch). Row + halo staged in LDS.
template<int K>
__global__ void __launch_bounds__(512)
blur_w_mask_kern(const float* __restrict__ tmp, const float* __restrict__ mp, int eyeCh,
                 float* __restrict__ out, float sigma, unsigned int* __restrict__ maxArr)
{
    constexpr int PAD = K / 2;
    __shared__ float wk[K + 1];
    __shared__ float srow[W_ + 2 * PAD];
    __shared__ float red[8];
    const int tid = threadIdx.x;
    if (tid < K) { float t = (tid - PAD) / sigma; wk[tid] = expf(-0.5f * t * t); }
    __syncthreads();
    if (tid == 0) { float s = 0.f; for (int k = 0; k < K; ++k) s += wk[k]; wk[K] = 1.f / s; }
    __syncthreads();
    if (tid < K) wk[tid] *= wk[K];

    const int h = blockIdx.x, b = blockIdx.y;
    const float* trow = tmp + (long)b * HW_ + (long)h * W_;
    for (int j = tid; j < W_ + 2 * PAD; j += 512) {
        int wi = j - PAD;
        wi = (wi < 0) ? -wi : wi;
        wi = (wi >= W_) ? (2 * W_ - 2 - wi) : wi;
        srow[j] = trow[wi];
    }
    __syncthreads();

    float acc = 0.f;
#pragma unroll
    for (int k = 0; k < K; ++k) acc = fmaf(srow[tid + k], wk[k], acc);

    const long rowoff = (long)b * (long)C_ * HW_ + (long)h * W_ + tid;
    const float eyes = mp[rowoff + (long)eyeCh * HW_];
    const float bg   = mp[rowoff];  // channel 0
    const float v = acc * (1.f - eyes) * (1.f - bg);
    out[(long)b * HW_ + (long)h * W_ + tid] = v;

    // block max reduce -> one atomicMax per block (v >= 0 so uint-bit order OK)
    float m = v;
#pragma unroll
    for (int off = 32; off > 0; off >>= 1) m = fmaxf(m, __shfl_down(m, off));
    if ((tid & 63) == 0) red[tid >> 6] = m;
    __syncthreads();
    if (tid == 0) {
        float mm = red[0];
        for (int i = 1; i < 8; ++i) mm = fmaxf(mm, red[i]);
        atomicMax(maxArr + b, __float_as_uint(mm));
    }
}

// ---------------- vertical (along W) blur + deterministic row partial sums ----
template<int K>
__global__ void __launch_bounds__(512)
blur_w_sum_kern(const float* __restrict__ tmp, float* __restrict__ out,
                float sigma, float* __restrict__ partials)
{
    constexpr int PAD = K / 2;
    __shared__ float wk[K + 1];
    __shared__ float srow[W_ + 2 * PAD];
    __shared__ float red[8];
    const int tid = threadIdx.x;
    if (tid < K) { float t = (tid - PAD) / sigma; wk[tid] = expf(-0.5f * t * t); }
    __syncthreads();
    if (tid == 0) { float s = 0.f; for (int k = 0; k < K; ++k) s += wk[k]; wk[K] = 1.f / s; }
    __syncthreads();
    if (tid < K) wk[tid] *= wk[K];

    const int h = blockIdx.x, b = blockIdx.y;
    const float* trow = tmp + (long)b * HW_ + (long)h * W_;
    for (int j = tid; j < W_ + 2 * PAD; j += 512) {
        int wi = j - PAD;
        wi = (wi < 0) ? -wi : wi;
        wi = (wi >= W_) ? (2 * W_ - 2 - wi) : wi;
        srow[j] = trow[wi];
    }
    __syncthreads();

    float acc = 0.f;
#pragma unroll
    for (int k = 0; k < K; ++k) acc = fmaf(srow[tid + k], wk[k], acc);
    out[(long)b * HW_ + (long)h * W_ + tid] = acc;

    float s = acc;
#pragma unroll
    for (int off = 32; off > 0; off >>= 1) s += __shfl_down(s, off);
    if ((tid & 63) == 0) red[tid >> 6] = s;
    __syncthreads();
    if (tid == 0) {
        float t = 0.f;
        for (int i = 0; i < 8; ++i) t += red[i];
        partials[(long)b * H_ + h] = t;
    }
}

// ---------------- einsum over channels + add normalized eye masks ----------
__global__ void __launch_bounds__(256)
combine_kern(const float* __restrict__ mp, const float* __restrict__ aw,
             const float* __restrict__ esw, const float* __restrict__ wl,
             const float* __restrict__ wr, const float* __restrict__ mx,
             float* __restrict__ out)
{
    __shared__ float saw[C_];
    const int tid = threadIdx.x;
    if (tid < C_) saw[tid] = aw[tid];
    __syncthreads();
    const int b = blockIdx.y;
    const long p = ((long)blockIdx.x * 256 + tid) * 4;
    const float* mpb = mp + (long)b * C_ * HW_ + p;
    float4 acc = make_float4(0.f, 0.f, 0.f, 0.f);
#pragma unroll
    for (int c = 0; c < C_; ++c) {
        const float4 v = *(const float4*)(mpb + (long)c * HW_);
        const float a = saw[c];
        acc.x = fmaf(v.x, a, acc.x);
        acc.y = fmaf(v.y, a, acc.y);
        acc.z = fmaf(v.z, a, acc.z);
        acc.w = fmaf(v.w, a, acc.w);
    }
    const float e  = esw[0];
    const float sl = e / mx[b];
    const float sr = e / mx[8 + b];
    const float4 l = *(const float4*)(wl + (long)b * HW_ + p);
    const float4 r = *(const float4*)(wr + (long)b * HW_ + p);
    float4 o;
    o.x = acc.x + l.x * sl + r.x * sr;
    o.y = acc.y + l.y * sl + r.y * sr;
    o.z = acc.z + l.z * sl + r.z * sr;
    o.w = acc.w + l.w * sl + r.w * sr;
    *(float4*)(out + (long)b * HW_ + p) = o;
}

// ---------------- deterministic final reductions ----------------
__global__ void __launch_bounds__(512)
reduce_rows_kern(const float* __restrict__ partials, float* __restrict__ sums)
{
    __shared__ float red[8];
    const int b = blockIdx.x, tid = threadIdx.x;
    float s = partials[(long)b * H_ + tid];
#pragma unroll
    for (int off = 32; off > 0; off >>= 1) s += __shfl_down(s, off);
    if ((tid & 63) == 0) red[tid >> 6] = s;
    __syncthreads();
    if (tid == 0) { float t = 0.f; for (int i = 0; i < 8; ++i) t += red[i]; sums[b] = t; }
}

__global__ void __launch_bounds__(256)
scale_kern(float* __restrict__ out, const float* __restrict__ sums)
{
    const int b = blockIdx.y;
    const long p = ((long)blockIdx.x * 256 + threadIdx.x) * 4;
    const float s = (float)HW_ / sums[b];
    float4 v = *(float4*)(out + (long)b * HW_ + p);
    v.x *= s; v.y *= s; v.z *= s; v.w *= s;
    *(float4*)(out + (long)b * HW_ + p) = v;
}

extern "C" void kernel_launch(void* const* d_in, const int* in_sizes, int n_in,
                              void* d_out, int out_size, void* d_ws, size_t ws_size,
                              hipStream_t stream)
{
    const float* mp  = (const float*)d_in[0];  // (8,19,512,512) f32
    const float* aw  = (const float*)d_in[1];  // (19,) f32
    const float* esw = (const float*)d_in[2];  // (1,) f32
    float* out = (float*)d_out;                // (8,1,512,512) f32

    // workspace layout (floats):
    //   [0..15]   maxbuf as uint bits (maxL 8, maxR 8)
    //   [16..23]  sums
    //   [64..64+4096) row partial sums
    //   [8192..)  t0, t1 image temps (B*HW each)
    float* wsf = (float*)d_ws;
    unsigned int* maxbuf = (unsigned int*)wsf;
    float* sums     = wsf + 16;
    float* partials = wsf + 64;
    float* t0 = wsf + 8192;
    float* t1 = t0 + (long)B_ * HW_;
    float* t2 = out;  // d_out doubles as w_r buffer (dead before final blur writes out)

    hipMemsetAsync(d_ws, 0, 64 * sizeof(float), stream);

    const dim3 gH(W_ / 256, H_ / 8, B_);
    const dim3 gW(H_, B_);
    const dim3 gP(HW_ / 4 / 256, B_);

    // left eye (channel 4): blurH -> t0, blurW*mask -> t1, max -> maxbuf[0..7]
    blur_h_kern<51, 8><<<gH, 256, 0, stream>>>(mp + (long)4 * HW_, (long)C_ * HW_, t0, 15.f);
    blur_w_mask_kern<51><<<gW, 512, 0, stream>>>(t0, mp, 4, t1, 15.f, maxbuf);
    // right eye (channel 5): blurH -> t0 (reuse), blurW*mask -> t2(=out), max -> maxbuf[8..15]
    blur_h_kern<51, 8><<<gH, 256, 0, stream>>>(mp + (long)5 * HW_, (long)C_ * HW_, t0, 15.f);
    blur_w_mask_kern<51><<<gW, 512, 0, stream>>>(t0, mp, 5, t2, 15.f, maxbuf + 8);
    // einsum + normalized eye masks -> t0
    combine_kern<<<gP, 256, 0, stream>>>(mp, aw, esw, t1, t2, (const float*)maxbuf, t0);
    // final 21-tap blur: H -> t1, W + partial sums -> out
    blur_h_kern<21, 8><<<gH, 256, 0, stream>>>(t0, (long)HW_, t1, 2.f);
    blur_w_sum_kern<21><<<gW, 512, 0, stream>>>(t1, out, 2.f, partials);
    reduce_rows_kern<<<B_, 512, 0, stream>>>(partials, sums);
    scale_kern<<<gP, 256, 0, stream>>>(out, sums);
}

// Round 2
// 126.006 us; speedup vs baseline: 1.6615x; 1.6615x over previous
//
#include <hip/hip_runtime.h>

// (B,C,H,W) = (8,19,512,512), fp32 everywhere.
constexpr int B_ = 8, C_ = 19, H_ = 512, W_ = 512;
constexpr int HW_ = H_ * W_;

// ---------------- horizontal (along H) 51-tap blur, both eyes ----------------
// Block: 256 threads over w; each thread produces TH consecutive h outputs via
// a register sliding window. Reflect: i<0 -> -i ; i>=H -> 2H-2-i.
template<int K, int TH>
__global__ void __launch_bounds__(256)
blur_h_eyes_kern(const float* __restrict__ mp, float* __restrict__ dst, float sigma)
{
    constexpr int PAD = K / 2;
    constexpr int NV = TH + K - 1;
    __shared__ float wk[K + 1];
    const int tid = threadIdx.x;
    if (tid < K) { float t = (tid - PAD) / sigma; wk[tid] = expf(-0.5f * t * t); }
    __syncthreads();
    if (tid == 0) { float s = 0.f; for (int k = 0; k < K; ++k) s += wk[k]; wk[K] = 1.f / s; }
    __syncthreads();
    if (tid < K) wk[tid] *= wk[K];
    __syncthreads();

    const int w   = blockIdx.x * 256 + tid;
    const int hb  = blockIdx.y * TH;
    const int z   = blockIdx.z;           // z = eye*B + b
    const int eye = z >> 3, b = z & 7;
    const float* sb = mp + ((long)b * C_ + 4 + eye) * HW_;
    float* db = dst + (long)z * HW_;

    float vals[NV];
#pragma unroll
    for (int j = 0; j < NV; ++j) {
        int r = hb - PAD + j;
        r = (r < 0) ? -r : r;
        r = (r >= H_) ? (2 * H_ - 2 - r) : r;
        vals[j] = sb[(long)r * W_ + w];
    }
#pragma unroll
    for (int o = 0; o < TH; ++o) {
        float acc = 0.f;
#pragma unroll
        for (int k = 0; k < K; ++k) acc = fmaf(vals[o + k], wk[k], acc);
        db[(long)(hb + o) * W_ + w] = acc;
    }
}

// -------- vertical (along W) 51-tap blur + eye-mask multiply + per-row max ---
// One 512-thread block per (row, eye*B+b). Row + halo staged in LDS.
// Writes deterministic per-row max (no atomics, no init needed).
template<int K>
__global__ void __launch_bounds__(512)
blur_w_mask_kern(const float* __restrict__ tmp, const float* __restrict__ mp,
                 float* __restrict__ outL, float* __restrict__ outR,
                 float sigma, float* __restrict__ rowmax)
{
    constexpr int PAD = K / 2;
    __shared__ float wk[K + 1];
    __shared__ float srow[W_ + 2 * PAD];
    __shared__ float red[8];
    const int tid = threadIdx.x;
    if (tid < K) { float t = (tid - PAD) / sigma; wk[tid] = expf(-0.5f * t * t); }
    __syncthreads();
    if (tid == 0) { float s = 0.f; for (int k = 0; k < K; ++k) s += wk[k]; wk[K] = 1.f / s; }
    __syncthreads();
    if (tid < K) wk[tid] *= wk[K];

    const int h = blockIdx.x;
    const int z = blockIdx.y;             // eye*B + b
    const int eye = z >> 3, b = z & 7;
    const float* trow = tmp + (long)z * HW_ + (long)h * W_;
    for (int j = tid; j < W_ + 2 * PAD; j += 512) {
        int wi = j - PAD;
        wi = (wi < 0) ? -wi : wi;
        wi = (wi >= W_) ? (2 * W_ - 2 - wi) : wi;
        srow[j] = trow[wi];
    }
    __syncthreads();

    float acc = 0.f;
#pragma unroll
    for (int k = 0; k < K; ++k) acc = fmaf(srow[tid + k], wk[k], acc);

    const long rowoff = (long)b * (long)C_ * HW_ + (long)h * W_ + tid;
    const float eyes = mp[rowoff + (long)(4 + eye) * HW_];
    const float bg   = mp[rowoff];  // channel 0
    const float v = acc * (1.f - eyes) * (1.f - bg);
    float* o = eye ? outR : outL;
    o[(long)b * HW_ + (long)h * W_ + tid] = v;

    float m = v;
#pragma unroll
    for (int off = 32; off > 0; off >>= 1) m = fmaxf(m, __shfl_down(m, off));
    if ((tid & 63) == 0) red[tid >> 6] = m;
    __syncthreads();
    if (tid == 0) {
        float mm = red[0];
        for (int i = 1; i < 8; ++i) mm = fmaxf(mm, red[i]);
        rowmax[(long)z * H_ + h] = mm;
    }
}

// ---------------- per-(eye,batch) max over 512 row-maxes ----------------
__global__ void __launch_bounds__(512)
rowmax_reduce_kern(const float* __restrict__ rowmax, float* __restrict__ mx)
{
    __shared__ float red[8];
    const int i = blockIdx.x, tid = threadIdx.x;
    float m = rowmax[(long)i * H_ + tid];
#pragma unroll
    for (int off = 32; off > 0; off >>= 1) m = fmaxf(m, __shfl_down(m, off));
    if ((tid & 63) == 0) red[tid >> 6] = m;
    __syncthreads();
    if (tid == 0) {
        float mm = red[0];
        for (int k = 1; k < 8; ++k) mm = fmaxf(mm, red[k]);
        mx[i] = mm;
    }
}

// ---------------- einsum over channels + add normalized eye masks ----------
__global__ void __launch_bounds__(256)
combine_kern(const float* __restrict__ mp, const float* __restrict__ aw,
             const float* __restrict__ esw, const float* __restrict__ wl,
             const float* __restrict__ wr, const float* __restrict__ mx,
             float* __restrict__ out)
{
    __shared__ float saw[C_];
    const int tid = threadIdx.x;
    if (tid < C_) saw[tid] = aw[tid];
    __syncthreads();
    const int b = blockIdx.y;
    const long p = ((long)blockIdx.x * 256 + tid) * 4;
    const float* mpb = mp + (long)b * C_ * HW_ + p;
    float4 acc = make_float4(0.f, 0.f, 0.f, 0.f);
#pragma unroll
    for (int c = 0; c < C_; ++c) {
        const float4 v = *(const float4*)(mpb + (long)c * HW_);
        const float a = saw[c];
        acc.x = fmaf(v.x, a, acc.x);
        acc.y = fmaf(v.y, a, acc.y);
        acc.z = fmaf(v.z, a, acc.z);
        acc.w = fmaf(v.w, a, acc.w);
    }
    const float e  = esw[0];
    const float sl = e / mx[b];
    const float sr = e / mx[8 + b];
    const float4 l = *(const float4*)(wl + (long)b * HW_ + p);
    const float4 r = *(const float4*)(wr + (long)b * HW_ + p);
    float4 o;
    o.x = acc.x + l.x * sl + r.x * sr;
    o.y = acc.y + l.y * sl + r.y * sr;
    o.z = acc.z + l.z * sl + r.z * sr;
    o.w = acc.w + l.w * sl + r.w * sr;
    *(float4*)(out + (long)b * HW_ + p) = o;
}

// -------- fused 21-tap separable blur (H then W) + per-tile partial sums ----
// One 256-thread block per (8-row tile, batch). 28x512 input rows in LDS,
// H-blur into registers, write back, W-blur with inline reflect.
__global__ void __launch_bounds__(256)
blur21_fused_kern(const float* __restrict__ src, float* __restrict__ out,
                  float* __restrict__ partials)
{
    constexpr int K = 21, PAD = 10, TH = 8;
    __shared__ float wk[K + 1];
    __shared__ float sin_[TH + 2 * PAD][W_];  // 28*512*4 = 57344 B
    __shared__ float red[4];
    const int tid = threadIdx.x;
    if (tid < K) { float t = (tid - PAD) * 0.5f; wk[tid] = expf(-0.5f * t * t); }
    __syncthreads();
    if (tid == 0) { float s = 0.f; for (int k = 0; k < K; ++k) s += wk[k]; wk[K] = 1.f / s; }
    __syncthreads();
    if (tid < K) wk[tid] *= wk[K];

    const int tile = blockIdx.x;   // 0..63
    const int b = blockIdx.y;
    const int hb = tile * TH;
    const float* sb = src + (long)b * HW_;

    for (int i = tid; i < (TH + 2 * PAD) * W_; i += 256) {
        const int r = i >> 9, c = i & 511;
        int rr = hb - PAD + r;
        rr = (rr < 0) ? -rr : rr;
        rr = (rr >= H_) ? (2 * H_ - 2 - rr) : rr;
        (&sin_[0][0])[i] = sb[(long)rr * W_ + c];
    }
    __syncthreads();

    float hv[16];
#pragma unroll
    for (int j = 0; j < 16; ++j) {
        const int i = j * 256 + tid;
        const int r = i >> 9, c = i & 511;
        float acc = 0.f;
#pragma unroll
        for (int k = 0; k < K; ++k) acc = fmaf(sin_[r + k][c], wk[k], acc);
        hv[j] = acc;
    }
    __syncthreads();
#pragma unroll
    for (int j = 0; j < 16; ++j) (&sin_[0][0])[j * 256 + tid] = hv[j];
    __syncthreads();

    float psum = 0.f;
#pragma unroll
    for (int j = 0; j < 16; ++j) {
        const int i = j * 256 + tid;
        const int r = i >> 9, c = i & 511;
        float acc = 0.f;
#pragma unroll
        for (int k = 0; k < K; ++k) {
            int cc = c - PAD + k;
            cc = (cc < 0) ? -cc : cc;
            cc = (cc >= W_) ? (2 * W_ - 2 - cc) : cc;
            acc = fmaf(sin_[r][cc], wk[k], acc);
        }
        out[(long)b * HW_ + (long)(hb + r) * W_ + c] = acc;
        psum += acc;
    }
#pragma unroll
    for (int off = 32; off > 0; off >>= 1) psum += __shfl_down(psum, off);
    if ((tid & 63) == 0) red[tid >> 6] = psum;
    __syncthreads();
    if (tid == 0) partials[(long)b * 64 + tile] = red[0] + red[1] + red[2] + red[3];
}

// ---------------- deterministic final reductions ----------------
__global__ void __launch_bounds__(64)
reduce_partials_kern(const float* __restrict__ partials, float* __restrict__ sums)
{
    const int b = blockIdx.x, tid = threadIdx.x;
    float s = partials[(long)b * 64 + tid];
#pragma unroll
    for (int off = 32; off > 0; off >>= 1) s += __shfl_down(s, off);
    if (tid == 0) sums[b] = s;
}

__global__ void __launch_bounds__(256)
scale_kern(float* __restrict__ out, const float* __restrict__ sums)
{
    const int b = blockIdx.y;
    const long p = ((long)blockIdx.x * 256 + threadIdx.x) * 4;
    const float s = (float)HW_ / sums[b];
    float4 v = *(float4*)(out + (long)b * HW_ + p);
    v.x *= s; v.y *= s; v.z *= s; v.w *= s;
    *(float4*)(out + (long)b * HW_ + p) = v;
}

extern "C" void kernel_launch(void* const* d_in, const int* in_sizes, int n_in,
                              void* d_out, int out_size, void* d_ws, size_t ws_size,
                              hipStream_t stream)
{
    const float* mp  = (const float*)d_in[0];  // (8,19,512,512) f32
    const float* aw  = (const float*)d_in[1];  // (19,) f32
    const float* esw = (const float*)d_in[2];  // (1,) f32
    float* out = (float*)d_out;                // (8,1,512,512) f32

    // workspace layout (floats):
    //   [0..15]    mx  (L 8, R 8)
    //   [16..23]   sums
    //   [64..576)  tile partial sums (8*64)
    //   [1024..9216)  rowmax (16*512)
    //   [16384..)  t0 (2*B*HW: hblur L,R; later combine out), t1 (B*HW: w_l)
    float* wsf = (float*)d_ws;
    float* mx       = wsf;
    float* sums     = wsf + 16;
    float* partials = wsf + 64;
    float* rowmax   = wsf + 1024;
    float* t0 = wsf + 16384;               // 2 images (L,R h-blur)
    float* t1 = t0 + 2L * B_ * HW_;        // w_l (unnormalized)
    float* t2 = out;                       // w_r (d_out dead until final blur)

    const dim3 gH(W_ / 256, H_ / 8, 2 * B_);
    const dim3 gW(H_, 2 * B_);
    const dim3 gP(HW_ / 4 / 256, B_);
    const dim3 gT(H_ / 8, B_);

    // eye blurs (both eyes in one launch each)
    blur_h_eyes_kern<51, 8><<<gH, 256, 0, stream>>>(mp, t0, 15.f);
    blur_w_mask_kern<51><<<gW, 512, 0, stream>>>(t0, mp, t1, t2, 15.f, rowmax);
    rowmax_reduce_kern<<<16, 512, 0, stream>>>(rowmax, mx);
    // einsum + normalized eye masks -> t0 (reuse)
    combine_kern<<<gP, 256, 0, stream>>>(mp, aw, esw, t1, t2, mx, t0);
    // final 21-tap blur (fused H+W) + partial sums -> out
    blur21_fused_kern<<<gT, 256, 0, stream>>>(t0, out, partials);
    reduce_partials_kern<<<B_, 64, 0, stream>>>(partials, sums);
    scale_kern<<<gP, 256, 0, stream>>>(out, sums);
}

// Round 4
// 123.249 us; speedup vs baseline: 1.6987x; 1.0224x over previous
//
#include <hip/hip_runtime.h>
#include <hip/hip_cooperative_groups.h>

namespace cg = cooperative_groups;

// (B,C,H,W) = (8,19,512,512), fp32 everywhere.
constexpr int B_ = 8, C_ = 19, H_ = 512, W_ = 512;
constexpr int HW_ = H_ * W_;
constexpr int NB = 512;   // mega: blocks (target 2/CU on 256 CUs)
constexpr int NT = 512;   // mega: threads (8 waves)

__device__ __forceinline__ int refl(int i, int n) {
    i = (i < 0) ? -i : i;
    return (i >= n) ? (2 * n - 2 - i) : i;
}

// Gaussian weights, normalized, into wk[0..K]; needs wk[K+1] slots.
template<int K>
__device__ __forceinline__ void make_wk(float* wk, float sigma, int tid) {
    if (tid < K) { float t = (tid - K / 2) / sigma; wk[tid] = expf(-0.5f * t * t); }
    __syncthreads();
    if (tid == 0) { float s = 0.f; for (int k = 0; k < K; ++k) s += wk[k]; wk[K] = 1.f / s; }
    __syncthreads();
    if (tid < K) wk[tid] *= wk[K];
    __syncthreads();
}

// workspace layout (floats):
//   [0..8192)      rowmax (z*512+h, z = eye*8+b)
//   [8192..8704)   partials (b*64+tile)
//   [16384..)      t0: 16 images (z = eye*8+b); eye blurs in-place,
//                  combine output overwrites images 8..15 in-place.

// ===================== cooperative mega kernel =====================
// Static LDS: 14400 floats = 57.6 KB (<=64 KB so the runtime occupancy
// check allows 2 blocks/CU -> 512 co-resident blocks).
__global__ void __launch_bounds__(NT, 4)
mega_kern(const float* __restrict__ mp, const float* __restrict__ aw,
          const float* __restrict__ esw, float* __restrict__ out,
          float* __restrict__ ws)
{
    cg::grid_group grid = cg::this_grid();
    __shared__ float lds[14400];
    float* wk = lds + 14336;   // 64 slots
    const int tid = threadIdx.x, bid = blockIdx.x;

    float* rowmax   = ws;
    float* partials = ws + 8192;
    float* t0       = ws + 16384;

    // ---------- P1: H-blur 51 (along h), both eyes, 16 rows/block ----------
    {
        make_wk<51>(wk, 15.f, tid);
        const int z = bid >> 5, hb = (bid & 31) * 16;
        const int eye = z >> 3, b = z & 7;
        const float* sb = mp + ((long)b * C_ + 4 + eye) * HW_;
        float* db = t0 + (long)z * HW_;
        float vals[66];
#pragma unroll
        for (int j = 0; j < 66; ++j) vals[j] = sb[(long)refl(hb - 25 + j, H_) * W_ + tid];
#pragma unroll
        for (int o = 0; o < 16; ++o) {
            float acc = 0.f;
#pragma unroll
            for (int k = 0; k < 51; ++k) acc = fmaf(vals[o + k], wk[k], acc);
            db[(long)(hb + o) * W_ + tid] = acc;
        }
    }
    grid.sync();

    // ---------- P2: W-blur 51 + mask, in-place, + per-row max --------------
    {
        float* srow = lds;          // 612
        float* red  = lds + 1024;   // 8
        for (int rj = 0; rj < 16; ++rj) {
            const int rowid = bid * 16 + rj;
            const int z = rowid >> 9, h = rowid & 511;
            const int eye = z >> 3, b = z & 7;
            float* trow = t0 + (long)z * HW_ + (long)h * W_;
            __syncthreads();
            for (int j = tid; j < 612; j += NT) srow[j] = trow[refl(j - 25, W_)];
            __syncthreads();
            float acc = 0.f;
#pragma unroll
            for (int k = 0; k < 51; ++k) acc = fmaf(srow[tid + k], wk[k], acc);
            const long rowoff = (long)b * C_ * HW_ + (long)h * W_ + tid;
            const float v = acc * (1.f - mp[rowoff + (long)(4 + eye) * HW_])
                                * (1.f - mp[rowoff]);
            trow[tid] = v;   // in-place (row staged before overwrite)
            float m = v;
#pragma unroll
            for (int off = 32; off; off >>= 1) m = fmaxf(m, __shfl_down(m, off));
            if ((tid & 63) == 0) red[tid >> 6] = m;
            __syncthreads();
            if (tid == 0) {
                float mm = red[0];
                for (int i = 1; i < 8; ++i) mm = fmaxf(mm, red[i]);
                rowmax[rowid] = mm;
            }
        }
    }
    grid.sync();

    // ---------- P4: einsum + normalized eye add, in-place into w_r ---------
    {
        float* red = lds + 1024;
        const int b0 = bid >> 7;                 // 128 blocks per batch
        float mxv[4];
        const int zz[4] = { b0, 8 + b0, 4 + b0, 12 + b0 };
        for (int q = 0; q < 4; ++q) {
            float m = rowmax[(long)zz[q] * 512 + tid];
#pragma unroll
            for (int off = 32; off; off >>= 1) m = fmaxf(m, __shfl_down(m, off));
            if ((tid & 63) == 0) red[tid >> 6] = m;
            __syncthreads();
            if (tid == 0) {
                float mm = red[0];
                for (int i = 1; i < 8; ++i) mm = fmaxf(mm, red[i]);
                red[0] = mm;
            }
            __syncthreads();
            mxv[q] = red[0];
            __syncthreads();
        }
        float* saw = lds;   // 19
        if (tid < 19) saw[tid] = aw[tid];
        __syncthreads();
        const float e = esw[0];
#pragma unroll
        for (int it = 0; it < 2; ++it) {
            const long g = (long)(it * NB + bid) * NT + tid;   // float4 idx
            const long b = g >> 16;
            const long p = (g & 65535) * 4;
            const float* mpb = mp + (long)b * C_ * HW_ + p;
            float4 acc = make_float4(0.f, 0.f, 0.f, 0.f);
#pragma unroll
            for (int c = 0; c < C_; ++c) {
                const float4 v = *(const float4*)(mpb + (long)c * HW_);
                const float a = saw[c];
                acc.x = fmaf(v.x, a, acc.x);
                acc.y = fmaf(v.y, a, acc.y);
                acc.z = fmaf(v.z, a, acc.z);
                acc.w = fmaf(v.w, a, acc.w);
            }
            const float sl = e / mxv[it * 2 + 0];   // L of this batch
            const float sr = e / mxv[it * 2 + 1];   // R of this batch
            const float4 l = *(const float4*)(t0 + (long)b * HW_ + p);
            float*      wr =                  t0 + (long)(8 + b) * HW_ + p;
            const float4 r = *(const float4*)wr;
            float4 o;
            o.x = fmaf(l.x, sl, fmaf(r.x, sr, acc.x));
            o.y = fmaf(l.y, sl, fmaf(r.y, sr, acc.y));
            o.z = fmaf(l.z, sl, fmaf(r.z, sr, acc.z));
            o.w = fmaf(l.w, sl, fmaf(r.w, sr, acc.w));
            *(float4*)wr = o;    // elementwise in-place
        }
    }
    grid.sync();

    // ---------- P5: fused 21-tap H+W blur, outputs in registers ------------
    float ov[8]; long obase; int myb;
    {
        make_wk<21>(wk, 2.f, tid);
        const int b = bid >> 6, tile = bid & 63, hb = tile * 8;
        myb = b;
        const float* sb = t0 + (long)(8 + b) * HW_;
        float* stage = lds;   // 28*512 = 14336
        for (int i = tid; i < 28 * 512; i += NT) {
            const int r = i >> 9, c = i & 511;
            stage[i] = sb[(long)refl(hb - 10 + r, H_) * W_ + c];
        }
        __syncthreads();
        float hv[8];
#pragma unroll
        for (int j = 0; j < 8; ++j) {
            float acc = 0.f;
#pragma unroll
            for (int k = 0; k < 21; ++k) acc = fmaf(stage[(j + k) * 512 + tid], wk[k], acc);
            hv[j] = acc;
        }
        __syncthreads();
#pragma unroll
        for (int j = 0; j < 8; ++j) stage[j * 512 + tid] = hv[j];   // in-place H rows
        __syncthreads();
        float psum = 0.f;
#pragma unroll
        for (int j = 0; j < 8; ++j) {
            float acc = 0.f;
#pragma unroll
            for (int k = 0; k < 21; ++k)
                acc = fmaf(stage[j * 512 + refl(tid - 10 + k, W_)], wk[k], acc);
            ov[j] = acc; psum += acc;
        }
        obase = (long)b * HW_ + (long)hb * W_;
#pragma unroll
        for (int off = 32; off; off >>= 1) psum += __shfl_down(psum, off);
        __syncthreads();
        if ((tid & 63) == 0) lds[tid >> 6] = psum;
        __syncthreads();
        if (tid == 0) {
            float s = 0.f;
            for (int i = 0; i < 8; ++i) s += lds[i];
            partials[bid] = s;
        }
    }
    grid.sync();

    // ---------- P6: scale by batch mean, single output write ---------------
    {
        const float* pp = partials + (long)myb * 64;
        float s = 0.f;
#pragma unroll
        for (int i = 0; i < 64; ++i) s += pp[i];   // uniform, deterministic
        const float scale = (float)HW_ / s;
#pragma unroll
        for (int j = 0; j < 8; ++j) out[obase + (long)j * W_ + tid] = ov[j] * scale;
    }
}

// ===================== fallback pipeline (5 kernels) =====================
__global__ void __launch_bounds__(256)
fb_hblur_kern(const float* __restrict__ mp, float* __restrict__ t0)
{
    __shared__ float wk[52];
    const int tid = threadIdx.x;
    make_wk<51>(wk, 15.f, tid);
    const int w  = blockIdx.x * 256 + tid;
    const int hb = blockIdx.y * 8;
    const int z  = blockIdx.z;
    const int eye = z >> 3, b = z & 7;
    const float* sb = mp + ((long)b * C_ + 4 + eye) * HW_;
    float* db = t0 + (long)z * HW_;
    float vals[58];
#pragma unroll
    for (int j = 0; j < 58; ++j) vals[j] = sb[(long)refl(hb - 25 + j, H_) * W_ + w];
#pragma unroll
    for (int o = 0; o < 8; ++o) {
        float acc = 0.f;
#pragma unroll
        for (int k = 0; k < 51; ++k) acc = fmaf(vals[o + k], wk[k], acc);
        db[(long)(hb + o) * W_ + w] = acc;
    }
}

__global__ void __launch_bounds__(512)
fb_wblur_mask_kern(float* __restrict__ t0, const float* __restrict__ mp,
                   float* __restrict__ rowmax)
{
    __shared__ float wk[52];
    __shared__ float srow[612];
    __shared__ float red[8];
    const int tid = threadIdx.x;
    make_wk<51>(wk, 15.f, tid);
    const int h = blockIdx.x, z = blockIdx.y;
    const int eye = z >> 3, b = z & 7;
    float* trow = t0 + (long)z * HW_ + (long)h * W_;
    for (int j = tid; j < 612; j += 512) srow[j] = trow[refl(j - 25, W_)];
    __syncthreads();
    float acc = 0.f;
#pragma unroll
    for (int k = 0; k < 51; ++k) acc = fmaf(srow[tid + k], wk[k], acc);
    const long rowoff = (long)b * C_ * HW_ + (long)h * W_ + tid;
    const float v = acc * (1.f - mp[rowoff + (long)(4 + eye) * HW_]) * (1.f - mp[rowoff]);
    trow[tid] = v;
    float m = v;
#pragma unroll
    for (int off = 32; off; off >>= 1) m = fmaxf(m, __shfl_down(m, off));
    if ((tid & 63) == 0) red[tid >> 6] = m;
    __syncthreads();
    if (tid == 0) {
        float mm = red[0];
        for (int i = 1; i < 8; ++i) mm = fmaxf(mm, red[i]);
        rowmax[(long)z * 512 + h] = mm;
    }
}

__global__ void __launch_bounds__(512)
fb_combine_kern(const float* __restrict__ mp, const float* __restrict__ aw,
                const float* __restrict__ esw, float* __restrict__ t0,
                const float* __restrict__ rowmax)
{
    __shared__ float saw[C_];
    __shared__ float red[8];
    __shared__ float mxs[2];
    const int tid = threadIdx.x;
    const int b = blockIdx.y;
    for (int q = 0; q < 2; ++q) {
        float m = rowmax[(long)(q * 8 + b) * 512 + tid];
#pragma unroll
        for (int off = 32; off; off >>= 1) m = fmaxf(m, __shfl_down(m, off));
        if ((tid & 63) == 0) red[tid >> 6] = m;
        __syncthreads();
        if (tid == 0) {
            float mm = red[0];
            for (int i = 1; i < 8; ++i) mm = fmaxf(mm, red[i]);
            mxs[q] = mm;
        }
        __syncthreads();
    }
    if (tid < C_) saw[tid] = aw[tid];
    __syncthreads();
    const long p = ((long)blockIdx.x * 512 + tid) * 4;
    const float* mpb = mp + (long)b * C_ * HW_ + p;
    float4 acc = make_float4(0.f, 0.f, 0.f, 0.f);
#pragma unroll
    for (int c = 0; c < C_; ++c) {
        const float4 v = *(const float4*)(mpb + (long)c * HW_);
        const float a = saw[c];
        acc.x = fmaf(v.x, a, acc.x);
        acc.y = fmaf(v.y, a, acc.y);
        acc.z = fmaf(v.z, a, acc.z);
        acc.w = fmaf(v.w, a, acc.w);
    }
    const float e = esw[0];
    const float sl = e / mxs[0], sr = e / mxs[1];
    const float4 l = *(const float4*)(t0 + (long)b * HW_ + p);
    float*      wr =                  t0 + (long)(8 + b) * HW_ + p;
    const float4 r = *(const float4*)wr;
    float4 o;
    o.x = fmaf(l.x, sl, fmaf(r.x, sr, acc.x));
    o.y = fmaf(l.y, sl, fmaf(r.y, sr, acc.y));
    o.z = fmaf(l.z, sl, fmaf(r.z, sr, acc.z));
    o.w = fmaf(l.w, sl, fmaf(r.w, sr, acc.w));
    *(float4*)wr = o;
}

__global__ void __launch_bounds__(512)
fb_blur21_kern(const float* __restrict__ t0, float* __restrict__ out,
               float* __restrict__ partials)
{
    __shared__ float lds[14400];
    float* wk = lds + 14336;
    const int tid = threadIdx.x;
    make_wk<21>(wk, 2.f, tid);
    const int tile = blockIdx.x, b = blockIdx.y, hb = tile * 8;
    const float* sb = t0 + (long)(8 + b) * HW_;
    float* stage = lds;
    for (int i = tid; i < 28 * 512; i += 512) {
        const int r = i >> 9, c = i & 511;
        stage[i] = sb[(long)refl(hb - 10 + r, H_) * W_ + c];
    }
    __syncthreads();
    float hv[8];
#pragma unroll
    for (int j = 0; j < 8; ++j) {
        float acc = 0.f;
#pragma unroll
        for (int k = 0; k < 21; ++k) acc = fmaf(stage[(j + k) * 512 + tid], wk[k], acc);
        hv[j] = acc;
    }
    __syncthreads();
#pragma unroll
    for (int j = 0; j < 8; ++j) stage[j * 512 + tid] = hv[j];
    __syncthreads();
    float psum = 0.f;
#pragma unroll
    for (int j = 0; j < 8; ++j) {
        float acc = 0.f;
#pragma unroll
        for (int k = 0; k < 21; ++k)
            acc = fmaf(stage[j * 512 + refl(tid - 10 + k, W_)], wk[k], acc);
        out[(long)b * HW_ + (long)(hb + j) * W_ + tid] = acc;
        psum += acc;
    }
#pragma unroll
    for (int off = 32; off; off >>= 1) psum += __shfl_down(psum, off);
    __syncthreads();
    if ((tid & 63) == 0) lds[tid >> 6] = psum;
    __syncthreads();
    if (tid == 0) {
        float s = 0.f;
        for (int i = 0; i < 8; ++i) s += lds[i];
        partials[(long)b * 64 + tile] = s;
    }
}

__global__ void __launch_bounds__(512)
fb_scale_kern(float* __restrict__ out, const float* __restrict__ partials)
{
    const int b = blockIdx.y;
    const float* pp = partials + (long)b * 64;
    float s = 0.f;
#pragma unroll
    for (int i = 0; i < 64; ++i) s += pp[i];
    const float scale = (float)HW_ / s;
    const long p = ((long)blockIdx.x * 512 + threadIdx.x) * 4;
    float4 v = *(float4*)(out + (long)b * HW_ + p);
    v.x *= scale; v.y *= scale; v.z *= scale; v.w *= scale;
    *(float4*)(out + (long)b * HW_ + p) = v;
}

extern "C" void kernel_launch(void* const* d_in, const int* in_sizes, int n_in,
                              void* d_out, int out_size, void* d_ws, size_t ws_size,
                              hipStream_t stream)
{
    const float* mp  = (const float*)d_in[0];
    const float* aw  = (const float*)d_in[1];
    const float* esw = (const float*)d_in[2];
    float* out = (float*)d_out;
    float* wsf = (float*)d_ws;
    float* rowmax   = wsf;
    float* partials = wsf + 8192;
    float* t0       = wsf + 16384;

    // Deterministic host-side decision (capture-safe: no stream ops).
    int coop = 0, nb = 0;
    hipDeviceGetAttribute(&coop, hipDeviceAttributeCooperativeLaunch, 0);
    hipOccupancyMaxActiveBlocksPerMultiprocessor(&nb, (const void*)mega_kern, NT, 0);

    if (coop && nb * 256 >= NB) {
        void* args[] = { (void*)&mp, (void*)&aw, (void*)&esw, (void*)&out, (void*)&wsf };
        hipLaunchCooperativeKernel((void*)mega_kern, dim3(NB), dim3(NT), args, 0, stream);
    } else {
        fb_hblur_kern<<<dim3(2, 64, 16), 256, 0, stream>>>(mp, t0);
        fb_wblur_mask_kern<<<dim3(512, 16), 512, 0, stream>>>(t0, mp, rowmax);
        fb_combine_kern<<<dim3(128, 8), 512, 0, stream>>>(mp, aw, esw, t0, rowmax);
        fb_blur21_kern<<<dim3(64, 8), 512, 0, stream>>>(t0, out, partials);
        fb_scale_kern<<<dim3(128, 8), 512, 0, stream>>>(out, partials);
    }
}

// Round 6
// 81.082 us; speedup vs baseline: 2.5821x; 1.5201x over previous
//
#include <hip/hip_runtime.h>
#include <hip/hip_cooperative_groups.h>

namespace cg = cooperative_groups;

// (B,C,H,W) = (8,19,512,512), fp32 everywhere.
constexpr int B_ = 8, C_ = 19, H_ = 512, W_ = 512;
constexpr int HW_ = H_ * W_;
constexpr int NB = 512;   // blocks (2/CU on 256 CUs)
constexpr int NT = 512;   // threads (8 waves)

__device__ __forceinline__ int refl(int i, int n) {
    i = (i < 0) ? -i : i;
    return (i >= n) ? (2 * n - 2 - i) : i;
}

// Distance-indexed normalized Gaussian weights in registers.
// ND = K/2+1 distinct values (kernel is symmetric); tap k -> wkr[|k - K/2|].
template<int ND>
__device__ __forceinline__ void gauss_reg(float (&wkr)[ND], float sigma) {
    float s = 0.f;
#pragma unroll
    for (int d = 0; d < ND; ++d) {
        const float t = d / sigma;
        wkr[d] = expf(-0.5f * t * t);
        s += (d ? 2.f : 1.f) * wkr[d];
    }
    const float inv = 1.f / s;
#pragma unroll
    for (int d = 0; d < ND; ++d) wkr[d] *= inv;
}

// workspace (floats):
//   [0..512)      blockmax (z*32 + htile), z = eye*8 + b
//   [1024..1536)  partials (b*64 + tile)
//   [16384..)     t0: 16 images (z = eye*8+b); combine overwrites images 8..15.

// ========== P12: fused eye pipeline (one 16-row tile of one eye image) ======
// Streaming H-blur 51 (acc in regs) -> LDS tile (+26-col reflected halo)
// -> W-blur 51 -> *(1-eyes)(1-bg) -> one global write + per-block max.
__device__ __forceinline__ void phase12(const float* __restrict__ mp,
                                        float* __restrict__ t0,
                                        float* __restrict__ blockmax,
                                        float* lds, int tid, int vb)
{
    float wkr[26];
    gauss_reg(wkr, 15.f);
    const int z = vb >> 5, hb = (vb & 31) * 16;
    const int eye = z >> 3, b = z & 7;
    const float* sb = mp + ((long)b * C_ + 4 + eye) * HW_;

    float acc[16];
#pragma unroll
    for (int o = 0; o < 16; ++o) acc[o] = 0.f;
#pragma unroll
    for (int j = 0; j < 66; ++j) {                    // rows hb-25 .. hb+40
        const float x = sb[(long)refl(hb - 25 + j, H_) * W_ + tid];
#pragma unroll
        for (int o = 0; o < 16; ++o) {
            const int k = j - o;                      // compile-time after unroll
            if (k >= 0 && k < 51)
                acc[o] = fmaf(x, wkr[(k < 25) ? (25 - k) : (k - 25)], acc[o]);
        }
    }
    float* tile = lds;                                // 16 x 564
#pragma unroll
    for (int o = 0; o < 16; ++o) tile[o * 564 + 26 + tid] = acc[o];  // acc dies here

    float mk[16];                                     // (1-eyes)(1-bg)
    const float* mrow = mp + (long)b * C_ * HW_ + (long)hb * W_ + tid;
#pragma unroll
    for (int o = 0; o < 16; ++o) {
        const float ey = mrow[(long)(4 + eye) * HW_ + (long)o * W_];
        const float bg = mrow[(long)o * W_];
        mk[o] = (1.f - ey) * (1.f - bg);
    }
    __syncthreads();
    if (tid < 416) {                                  // 16 rows x 26 halo cols
        const int o = tid / 26, c = tid - o * 26;     // c = 0..25
        tile[o * 564 + 25 - c]  = tile[o * 564 + 27 + c];    // col -(c+1) <- c+1
        tile[o * 564 + 538 + c] = tile[o * 564 + 536 - c];   // col 512+c <- 510-c
    }
    __syncthreads();

    float* db = t0 + (long)z * HW_ + (long)hb * W_ + tid;
    float vmax = 0.f;                                 // v >= 0
#pragma unroll
    for (int o = 0; o < 16; ++o) {
        float a2 = 0.f;
        const float* tr = tile + o * 564 + 1 + tid;   // tap k -> col tid-25+k
#pragma unroll
        for (int k = 0; k < 51; ++k)
            a2 = fmaf(tr[k], wkr[(k < 25) ? (25 - k) : (k - 25)], a2);
        const float v = a2 * mk[o];
        db[(long)o * W_] = v;
        vmax = fmaxf(vmax, v);
    }
#pragma unroll
    for (int off = 32; off; off >>= 1) vmax = fmaxf(vmax, __shfl_down(vmax, off));
    __syncthreads();                                  // tile dead; reuse lds[0..8)
    if ((tid & 63) == 0) lds[tid >> 6] = vmax;
    __syncthreads();
    if (tid == 0) {
        float m = lds[0];
        for (int i = 1; i < 8; ++i) m = fmaxf(m, lds[i]);
        blockmax[z * 32 + (vb & 31)] = m;
    }
}

// ========== P4: mx reduce + einsum over 19 ch + eye add (in-place) ==========
__device__ __forceinline__ void phase4(const float* __restrict__ mp,
                                       const float* __restrict__ aw,
                                       const float* __restrict__ esw,
                                       float* __restrict__ t0,
                                       const float* __restrict__ blockmax,
                                       float* lds, int tid, int bid)
{
    const int b0 = bid >> 7;            // batches b0 (it=0) and b0+4 (it=1)
    float mxv[4];
#pragma unroll
    for (int q = 0; q < 4; ++q) {
        const int z = (q & 1) * 8 + (q >> 1) * 4 + b0;  // L(b0),R(b0),L(b0+4),R(b0+4)
        const float* bm = blockmax + z * 32;
        float m = bm[0];
        for (int i = 1; i < 32; ++i) m = fmaxf(m, bm[i]);
        mxv[q] = m;
    }
    if (tid < C_) lds[tid] = aw[tid];
    __syncthreads();
    const float e = esw[0];
#pragma unroll
    for (int it = 0; it < 2; ++it) {
        const long g = (long)(it * NB + bid) * NT + tid;   // float4 index
        const long b = g >> 16;
        const long p = (g & 65535) * 4;
        const float* mpb = mp + (long)b * C_ * HW_ + p;
        float4 acc = make_float4(0.f, 0.f, 0.f, 0.f);
#pragma unroll
        for (int c = 0; c < C_; ++c) {
            const float4 v = *(const float4*)(mpb + (long)c * HW_);
            const float a = lds[c];
            acc.x = fmaf(v.x, a, acc.x);
            acc.y = fmaf(v.y, a, acc.y);
            acc.z = fmaf(v.z, a, acc.z);
            acc.w = fmaf(v.w, a, acc.w);
        }
        const float sl = e / mxv[it * 2 + 0];
        const float sr = e / mxv[it * 2 + 1];
        const float4 l = *(const float4*)(t0 + (long)b * HW_ + p);
        float*      wr =                  t0 + (long)(8 + b) * HW_ + p;
        const float4 r = *(const float4*)wr;
        float4 o;
        o.x = fmaf(l.x, sl, fmaf(r.x, sr, acc.x));
        o.y = fmaf(l.y, sl, fmaf(r.y, sr, acc.y));
        o.z = fmaf(l.z, sl, fmaf(r.z, sr, acc.z));
        o.w = fmaf(l.w, sl, fmaf(r.w, sr, acc.w));
        *(float4*)wr = o;
    }
}

// ========== P5: fused 21-tap H+W blur; outputs stay in registers ============
__device__ __forceinline__ void phase5(const float* __restrict__ t0,
                                       float* __restrict__ partials,
                                       float* lds, int tid, int vb,
                                       float (&ov)[8], long& obase, int& myb)
{
    float wkr[11];
    gauss_reg(wkr, 2.f);
    const int b = vb >> 6, tile6 = vb & 63, hb = tile6 * 8;
    myb = b;
    const float* sb = t0 + (long)(8 + b) * HW_;
    float* stage = lds;                                // 28 x 512
    for (int i = tid; i < 28 * 512; i += NT) {
        const int r = i >> 9, c = i & 511;
        stage[i] = sb[(long)refl(hb - 10 + r, H_) * W_ + c];
    }
    __syncthreads();
    float hv[8];
#pragma unroll
    for (int j = 0; j < 8; ++j) {
        float a = 0.f;
#pragma unroll
        for (int k = 0; k < 21; ++k)
            a = fmaf(stage[(j + k) * 512 + tid], wkr[(k < 10) ? (10 - k) : (k - 10)], a);
        hv[j] = a;
    }
    __syncthreads();
#pragma unroll
    for (int j = 0; j < 8; ++j) stage[j * 512 + tid] = hv[j];   // in-place H rows
    __syncthreads();
    float psum = 0.f;
#pragma unroll
    for (int j = 0; j < 8; ++j) {
        float a = 0.f;
#pragma unroll
        for (int k = 0; k < 21; ++k)
            a = fmaf(stage[j * 512 + refl(tid - 10 + k, W_)],
                     wkr[(k < 10) ? (10 - k) : (k - 10)], a);
        ov[j] = a; psum += a;
    }
    obase = (long)b * HW_ + (long)hb * W_;
#pragma unroll
    for (int off = 32; off; off >>= 1) psum += __shfl_down(psum, off);
    __syncthreads();
    if ((tid & 63) == 0) lds[tid >> 6] = psum;
    __syncthreads();
    if (tid == 0) {
        float s = 0.f;
        for (int i = 0; i < 8; ++i) s += lds[i];
        partials[b * 64 + tile6] = s;
    }
}

// ===================== cooperative mega kernel =====================
__global__ void __launch_bounds__(NT, 4)
mega_kern(const float* __restrict__ mp, const float* __restrict__ aw,
          const float* __restrict__ esw, float* __restrict__ out,
          float* __restrict__ ws)
{
    cg::grid_group grid = cg::this_grid();
    __shared__ float lds[14336];                 // 57344 B
    const int tid = threadIdx.x, bid = blockIdx.x;
    // XCD-chunked swizzle: consecutive vb share an XCD -> halo re-reads L2-local.
    const int vb = (bid & 7) * 64 + (bid >> 3);
    float* blockmax = ws;
    float* partials = ws + 1024;
    float* t0       = ws + 16384;

    phase12(mp, t0, blockmax, lds, tid, vb);
    grid.sync();
    phase4(mp, aw, esw, t0, blockmax, lds, tid, bid);
    grid.sync();
    float ov[8]; long obase; int myb;
    phase5(t0, partials, lds, tid, vb, ov, obase, myb);
    grid.sync();
    // P6: scale by batch mean, single scaled output write
    const float* pp = partials + (long)myb * 64;
    float s = 0.f;
#pragma unroll
    for (int i = 0; i < 64; ++i) s += pp[i];     // uniform, deterministic
    const float scale = (float)HW_ / s;
#pragma unroll
    for (int j = 0; j < 8; ++j) out[obase + (long)j * W_ + tid] = ov[j] * scale;
}

// ===================== fallback pipeline (4 kernels) =====================
__global__ void __launch_bounds__(NT)
fb_p12_kern(const float* __restrict__ mp, float* __restrict__ t0,
            float* __restrict__ blockmax)
{
    __shared__ float lds[9088];                  // 16*564 = 9024 (+pad)
    const int bid = blockIdx.x;
    const int vb = (bid & 7) * 64 + (bid >> 3);
    phase12(mp, t0, blockmax, lds, threadIdx.x, vb);
}

__global__ void __launch_bounds__(NT)
fb_p4_kern(const float* __restrict__ mp, const float* __restrict__ aw,
           const float* __restrict__ esw, float* __restrict__ t0,
           const float* __restrict__ blockmax)
{
    __shared__ float lds[32];
    phase4(mp, aw, esw, t0, blockmax, lds, threadIdx.x, blockIdx.x);
}

__global__ void __launch_bounds__(NT)
fb_p5_kern(const float* __restrict__ t0, float* __restrict__ out,
           float* __restrict__ partials)
{
    __shared__ float lds[14336];
    const int bid = blockIdx.x;
    const int vb = (bid & 7) * 64 + (bid >> 3);
    float ov[8]; long obase; int myb;
    phase5(t0, partials, lds, threadIdx.x, vb, ov, obase, myb);
#pragma unroll
    for (int j = 0; j < 8; ++j) out[obase + (long)j * W_ + threadIdx.x] = ov[j];
}

__global__ void __launch_bounds__(NT)
fb_scale_kern(float* __restrict__ out, const float* __restrict__ partials)
{
    const int b = blockIdx.y;
    const float* pp = partials + (long)b * 64;
    float s = 0.f;
#pragma unroll
    for (int i = 0; i < 64; ++i) s += pp[i];
    const float scale = (float)HW_ / s;
    const long p = ((long)blockIdx.x * NT + threadIdx.x) * 4;
    float4 v = *(float4*)(out + (long)b * HW_ + p);
    v.x *= scale; v.y *= scale; v.z *= scale; v.w *= scale;
    *(float4*)(out + (long)b * HW_ + p) = v;
}

extern "C" void kernel_launch(void* const* d_in, const int* in_sizes, int n_in,
                              void* d_out, int out_size, void* d_ws, size_t ws_size,
                              hipStream_t stream)
{
    const float* mp  = (const float*)d_in[0];  // (8,19,512,512) f32
    const float* aw  = (const float*)d_in[1];  // (19,) f32
    const float* esw = (const float*)d_in[2];  // (1,) f32
    float* out = (float*)d_out;                // (8,1,512,512) f32
    float* wsf = (float*)d_ws;
    float* blockmax = wsf;
    float* partials = wsf + 1024;
    float* t0       = wsf + 16384;

    // Deterministic host-side decision (capture-safe: host queries only).
    int coop = 0, nb = 0;
    hipDeviceGetAttribute(&coop, hipDeviceAttributeCooperativeLaunch, 0);
    hipOccupancyMaxActiveBlocksPerMultiprocessor(&nb, (const void*)mega_kern, NT, 0);

    if (coop && nb >= 2) {
        void* args[] = { (void*)&mp, (void*)&aw, (void*)&esw, (void*)&out, (void*)&wsf };
        hipLaunchCooperativeKernel((void*)mega_kern, dim3(NB), dim3(NT), args, 0, stream);
    } else {
        fb_p12_kern<<<NB, NT, 0, stream>>>(mp, t0, blockmax);
        fb_p4_kern<<<NB, NT, 0, stream>>>(mp, aw, esw, t0, blockmax);
        fb_p5_kern<<<NB, NT, 0, stream>>>(t0, out, partials);
        fb_scale_kern<<<dim3(HW_ / 4 / NT, B_), NT, 0, stream>>>(out, partials);
    }
}

// Round 7
// 69.890 us; speedup vs baseline: 2.9956x; 1.1601x over previous
//
#include <hip/hip_runtime.h>
#include <hip/hip_cooperative_groups.h>

namespace cg = cooperative_groups;

// (B,C,H,W) = (8,19,512,512), fp32 everywhere.
constexpr int B_ = 8, C_ = 19, H_ = 512, W_ = 512;
constexpr int HW_ = H_ * W_;
constexpr int NB = 512;   // blocks (2/CU on 256 CUs)
constexpr int NT = 512;   // threads (8 waves)

__device__ __forceinline__ int refl(int i, int n) {
    i = (i < 0) ? -i : i;
    return (i >= n) ? (2 * n - 2 - i) : i;
}

// Distance-indexed normalized Gaussian weights in registers.
// ND = K/2+1 distinct values; tap k -> wkr[|k - K/2|].
template<int ND>
__device__ __forceinline__ void gauss_reg(float (&wkr)[ND], float sigma) {
    float s = 0.f;
#pragma unroll
    for (int d = 0; d < ND; ++d) {
        const float t = d / sigma;
        wkr[d] = expf(-0.5f * t * t);
        s += (d ? 2.f : 1.f) * wkr[d];
    }
    const float inv = 1.f / s;
#pragma unroll
    for (int d = 0; d < ND; ++d) wkr[d] *= inv;
}

// Total-contribution weight of input position i under the K=21 reflect blur:
// sum(blur(x)) = sum_i x(i) * A(i) per separable dim.
// direct: o = i+10-t in [0,H);  left reflect (1<=i<=10): o = 10-t-i >= 0;
// right reflect (501<=i<=510): o = 1032-i-t < 512  <=>  t >= 521-i.
__device__ __forceinline__ float aweight(int i, const float (&wkr)[11]) {
    float a = 0.f;
#pragma unroll
    for (int t = 0; t < 21; ++t) {
        const float k = wkr[(t < 10) ? (10 - t) : (t - 10)];
        const int o = i + 10 - t;
        if (o >= 0 && o < H_) a += k;
        if (i >= 1 && i <= 10 && t <= 10 - i) a += k;
        if (i >= 501 && i <= 510 && t >= 521 - i) a += k;
    }
    return a;
}

// LDS map (floats), 14336 total:
//   [0..9024)      eye tile 16x564 / Phase-B stage 28x512 (fills all 14336)
//   [0..16)        reduce scratch (used only when tile region is dead)
//   [9216..9728)   A-weight table A[512]
//   [9728..9747)   area weights saw[19]
// workspace (floats):
//   [0..512)      blockmax (z*32 + htile), z = eye*8 + b
//   [512..1024)   eyesumw  (z*32 + htile): block's sum v*A(h)*A(w)
//   [1024..1536)  esum     (bid): block's einsum-chunk sum * A(h)*A(w)
//   [16384..)     t0: 24 images: z=0..7 w_l, 8..15 w_r, 16..23 einsum out

// ========== Phase A part 1: fused eye pipeline (16-row tile of one eye) ====
__device__ __forceinline__ void eye_tile(const float* __restrict__ mp,
                                         float* __restrict__ t0,
                                         float* __restrict__ blockmax,
                                         float* __restrict__ eyesumw,
                                         float* lds, int tid, int vb)
{
    float wkr[26];
    gauss_reg(wkr, 15.f);
    const int z = vb >> 5, hb = (vb & 31) * 16;
    const int eye = z >> 3, b = z & 7;
    const float* sb = mp + ((long)b * C_ + 4 + eye) * HW_;

    float acc[16];
#pragma unroll
    for (int o = 0; o < 16; ++o) acc[o] = 0.f;
#pragma unroll
    for (int j = 0; j < 66; ++j) {                    // rows hb-25 .. hb+40
        const float x = sb[(long)refl(hb - 25 + j, H_) * W_ + tid];
#pragma unroll
        for (int o = 0; o < 16; ++o) {
            const int k = j - o;                      // compile-time after unroll
            if (k >= 0 && k < 51)
                acc[o] = fmaf(x, wkr[(k < 25) ? (25 - k) : (k - 25)], acc[o]);
        }
    }
    float* tile = lds;                                // 16 x 564
    __syncthreads();                                  // tile region free of prior use
#pragma unroll
    for (int o = 0; o < 16; ++o) tile[o * 564 + 26 + tid] = acc[o];  // acc dies

    float mk[16];                                     // (1-eyes)(1-bg)
    const float* mrow = mp + (long)b * C_ * HW_ + (long)hb * W_ + tid;
#pragma unroll
    for (int o = 0; o < 16; ++o) {
        const float ey = mrow[(long)(4 + eye) * HW_ + (long)o * W_];
        const float bg = mrow[(long)o * W_];
        mk[o] = (1.f - ey) * (1.f - bg);
    }
    __syncthreads();
    if (tid < 416) {                                  // 16 rows x 26 halo cols
        const int o = tid / 26, c = tid - o * 26;     // c = 0..25
        tile[o * 564 + 25 - c]  = tile[o * 564 + 27 + c];    // col -(c+1) <- c+1
        tile[o * 564 + 538 + c] = tile[o * 564 + 536 - c];   // col 512+c <- 510-c
    }
    __syncthreads();

    const float* A = lds + 9216;
    const float Aw = A[tid];
    float* db = t0 + (long)z * HW_ + (long)hb * W_ + tid;
    float vmax = 0.f, vsum = 0.f;                     // v >= 0
#pragma unroll
    for (int o = 0; o < 16; ++o) {
        float a2 = 0.f;
        const float* tr = tile + o * 564 + 1 + tid;   // tap k -> col tid-25+k
#pragma unroll
        for (int k = 0; k < 51; ++k)
            a2 = fmaf(tr[k], wkr[(k < 25) ? (25 - k) : (k - 25)], a2);
        const float v = a2 * mk[o];
        db[(long)o * W_] = v;
        vmax = fmaxf(vmax, v);
        vsum = fmaf(v, A[hb + o] * Aw, vsum);
    }
#pragma unroll
    for (int off = 32; off; off >>= 1) {
        vmax = fmaxf(vmax, __shfl_down(vmax, off));
        vsum += __shfl_down(vsum, off);
    }
    __syncthreads();                                  // tile dead -> scratch ok
    if ((tid & 63) == 0) { lds[tid >> 6] = vmax; lds[8 + (tid >> 6)] = vsum; }
    __syncthreads();
    if (tid == 0) {
        float m = lds[0], s = lds[8];
        for (int i = 1; i < 8; ++i) { m = fmaxf(m, lds[i]); s += lds[8 + i]; }
        blockmax[z * 32 + (vb & 31)] = m;
        eyesumw[z * 32 + (vb & 31)] = s;
    }
}

// ========== Phase A part 2: einsum chunk + A-weighted sum ==================
__device__ __forceinline__ void einsum_part(const float* __restrict__ mp,
                                            float* __restrict__ t3,
                                            float* __restrict__ esum,
                                            float* lds, int tid, int bid)
{
    const float* A   = lds + 9216;
    const float* saw = lds + 9728;
    const int b = bid >> 6, chunk = bid & 63;
    float se = 0.f;
#pragma unroll
    for (int q = 0; q < 2; ++q) {
        const int p4 = chunk * 1024 + q * 512 + tid;  // float4 index in batch
        const long p = (long)p4 * 4;
        const int h = (int)(p >> 9), w0 = (int)(p & 511);
        const float* mpb = mp + (long)b * C_ * HW_ + p;
        float4 acc = make_float4(0.f, 0.f, 0.f, 0.f);
#pragma unroll
        for (int c = 0; c < C_; ++c) {
            const float4 v = *(const float4*)(mpb + (long)c * HW_);
            const float a = saw[c];
            acc.x = fmaf(v.x, a, acc.x);
            acc.y = fmaf(v.y, a, acc.y);
            acc.z = fmaf(v.z, a, acc.z);
            acc.w = fmaf(v.w, a, acc.w);
        }
        *(float4*)(t3 + (long)b * HW_ + p) = acc;
        const float dw = acc.x * A[w0] + acc.y * A[w0 + 1]
                       + acc.z * A[w0 + 2] + acc.w * A[w0 + 3];
        se = fmaf(dw, A[h], se);
    }
#pragma unroll
    for (int off = 32; off; off >>= 1) se += __shfl_down(se, off);
    __syncthreads();
    if ((tid & 63) == 0) lds[tid >> 6] = se;
    __syncthreads();
    if (tid == 0) {
        float s = 0.f;
        for (int i = 0; i < 8; ++i) s += lds[i];
        esum[bid] = s;
    }
}

// ========== Phase B: combine + fused 21-tap H+W blur + scaled write ========
__device__ __forceinline__ void phaseB(const float* __restrict__ esw,
                                       const float* __restrict__ t0,
                                       const float* __restrict__ blockmax,
                                       const float* __restrict__ eyesumw,
                                       const float* __restrict__ esum,
                                       float* __restrict__ out,
                                       float* lds, int tid, int vb)
{
    float wkr[11];
    gauss_reg(wkr, 2.f);
    const int b = vb >> 6, tile6 = vb & 63, hb = tile6 * 8;

    // uniform scalar reductions (identical in every thread)
    float mxL = blockmax[b * 32], mxR = blockmax[(8 + b) * 32];
    float SeL = 0.f, SeR = 0.f, Se = 0.f;
    for (int i = 0; i < 32; ++i) {
        mxL = fmaxf(mxL, blockmax[b * 32 + i]);
        mxR = fmaxf(mxR, blockmax[(8 + b) * 32 + i]);
        SeL += eyesumw[b * 32 + i];
        SeR += eyesumw[(8 + b) * 32 + i];
    }
    for (int i = 0; i < 64; ++i) Se += esum[b * 64 + i];
    const float e = esw[0];
    const float sl = e / mxL, sr = e / mxR;
    const float scale = (float)HW_ / (Se + sl * SeL + sr * SeR);

    const float* t1 = t0 + (long)b * HW_;
    const float* t2 = t0 + (long)(8 + b) * HW_;
    const float* t3 = t0 + (long)(16 + b) * HW_;
    float* stage = lds;                                // 28 x 512
    for (int i = tid; i < 28 * 512; i += NT) {
        const int r = i >> 9, c = i & 511;
        const long off = (long)refl(hb - 10 + r, H_) * W_ + c;
        stage[i] = fmaf(t1[off], sl, fmaf(t2[off], sr, t3[off]));
    }
    __syncthreads();
    float hv[8];
#pragma unroll
    for (int j = 0; j < 8; ++j) {
        float a = 0.f;
#pragma unroll
        for (int k = 0; k < 21; ++k)
            a = fmaf(stage[(j + k) * 512 + tid], wkr[(k < 10) ? (10 - k) : (k - 10)], a);
        hv[j] = a;
    }
    __syncthreads();
#pragma unroll
    for (int j = 0; j < 8; ++j) stage[j * 512 + tid] = hv[j];   // in-place H rows
    __syncthreads();
#pragma unroll
    for (int j = 0; j < 8; ++j) {
        float a = 0.f;
#pragma unroll
        for (int k = 0; k < 21; ++k)
            a = fmaf(stage[j * 512 + refl(tid - 10 + k, W_)],
                     wkr[(k < 10) ? (10 - k) : (k - 10)], a);
        out[(long)b * HW_ + (long)(hb + j) * W_ + tid] = a * scale;
    }
}

// ===================== cooperative mega kernel (1 grid.sync) ================
__global__ void __launch_bounds__(NT, 4)
mega_kern(const float* __restrict__ mp, const float* __restrict__ aw,
          const float* __restrict__ esw, float* __restrict__ out,
          float* __restrict__ ws)
{
    cg::grid_group grid = cg::this_grid();
    __shared__ float lds[14336];                 // 57344 B
    const int tid = threadIdx.x, bid = blockIdx.x;
    // XCD-chunked swizzle: consecutive vb share an XCD -> halo reads L2-local.
    const int vb = (bid & 7) * 64 + (bid >> 3);
    float* blockmax = ws;
    float* eyesumw  = ws + 512;
    float* esum     = ws + 1024;
    float* t0       = ws + 16384;
    float* t3       = t0 + 16L * HW_;

    // A-weight table + area weights into LDS (above tile region)
    {
        float w21[11];
        gauss_reg(w21, 2.f);
        lds[9216 + tid] = aweight(tid, w21);
    }
    if (tid < C_) lds[9728 + tid] = aw[tid];
    __syncthreads();

    // parity-alternated order: mixes compute-heavy and BW-heavy work chip-wide
    if (bid & 1) {
        einsum_part(mp, t3, esum, lds, tid, bid);
        eye_tile(mp, t0, blockmax, eyesumw, lds, tid, vb);
    } else {
        eye_tile(mp, t0, blockmax, eyesumw, lds, tid, vb);
        einsum_part(mp, t3, esum, lds, tid, bid);
    }
    grid.sync();
    phaseB(esw, t0, blockmax, eyesumw, esum, out, lds, tid, vb);
}

// ===================== fallback pipeline (2 kernels) =====================
__global__ void __launch_bounds__(NT)
fb_A_kern(const float* __restrict__ mp, const float* __restrict__ aw,
          float* __restrict__ ws)
{
    __shared__ float lds[14336];
    const int tid = threadIdx.x, bid = blockIdx.x;
    const int vb = (bid & 7) * 64 + (bid >> 3);
    float* blockmax = ws;
    float* eyesumw  = ws + 512;
    float* esum     = ws + 1024;
    float* t0       = ws + 16384;
    float* t3       = t0 + 16L * HW_;
    {
        float w21[11];
        gauss_reg(w21, 2.f);
        lds[9216 + tid] = aweight(tid, w21);
    }
    if (tid < C_) lds[9728 + tid] = aw[tid];
    __syncthreads();
    if (bid & 1) {
        einsum_part(mp, t3, esum, lds, tid, bid);
        eye_tile(mp, t0, blockmax, eyesumw, lds, tid, vb);
    } else {
        eye_tile(mp, t0, blockmax, eyesumw, lds, tid, vb);
        einsum_part(mp, t3, esum, lds, tid, bid);
    }
}

__global__ void __launch_bounds__(NT)
fb_B_kern(const float* __restrict__ esw, float* __restrict__ out,
          float* __restrict__ ws)
{
    __shared__ float lds[14336];
    const int tid = threadIdx.x, bid = blockIdx.x;
    const int vb = (bid & 7) * 64 + (bid >> 3);
    phaseB(esw, ws + 16384, ws, ws + 512, ws + 1024, out, lds, tid, vb);
}

extern "C" void kernel_launch(void* const* d_in, const int* in_sizes, int n_in,
                              void* d_out, int out_size, void* d_ws, size_t ws_size,
                              hipStream_t stream)
{
    const float* mp  = (const float*)d_in[0];  // (8,19,512,512) f32
    const float* aw  = (const float*)d_in[1];  // (19,) f32
    const float* esw = (const float*)d_in[2];  // (1,) f32
    float* out = (float*)d_out;                // (8,1,512,512) f32
    float* wsf = (float*)d_ws;

    // Deterministic host-side decision (capture-safe: host queries only).
    int coop = 0, nb = 0;
    hipDeviceGetAttribute(&coop, hipDeviceAttributeCooperativeLaunch, 0);
    hipOccupancyMaxActiveBlocksPerMultiprocessor(&nb, (const void*)mega_kern, NT, 0);

    if (coop && nb >= 2) {
        void* args[] = { (void*)&mp, (void*)&aw, (void*)&esw, (void*)&out, (void*)&wsf };
        hipLaunchCooperativeKernel((void*)mega_kern, dim3(NB), dim3(NT), args, 0, stream);
    } else {
        fb_A_kern<<<NB, NT, 0, stream>>>(mp, aw, wsf);
        fb_B_kern<<<NB, NT, 0, stream>>>(esw, out, wsf);
    }
}